// Round 11
// baseline (333.234 us; speedup 1.0000x reference)
//
#include <hip/hip_runtime.h>
#include <math.h>

#define HID 128
#define POOL_SEG 16
#define WT_STRIDE 136     // padded k-stride (shorts) for transposed bf16 W
#define ELL_D 48          // ELL slots/node (deg~Binom mean16 sd4; P(>48)~1e-15)
#define SC_CHUNK 2048     // edges per scatter block-chunk
#define FXS 16384.0f      // fixed-point scale (2^14) for deterministic edge sums
#define FXI (1.0f/16384.0f)
#define FG_KC 12          // final-gemm k-chunks (768 = 12 * 64)
#define BIN_TPB 256
#define BIN_EPT 16
#define BIN_EPB (BIN_TPB * BIN_EPT)   // 4096 edges per bin block

typedef __attribute__((ext_vector_type(8))) short short8;   // 8 bf16 = 4 VGPRs
typedef __attribute__((ext_vector_type(4))) float float4v;  // 4 fp32 acc

__device__ inline short f2bf(float f) {
  unsigned u = __builtin_bit_cast(unsigned, f);
  unsigned r = (u + 0x7fff + ((u >> 16) & 1)) >> 16;   // RNE
  return (short)r;
}
__device__ inline unsigned pack2bf(float lo, float hi) {
  return (unsigned)(unsigned short)f2bf(lo) | ((unsigned)(unsigned short)f2bf(hi) << 16);
}
__device__ inline float bflo(unsigned u) { return __builtin_bit_cast(float, u << 16); }
__device__ inline float bfhi(unsigned u) { return __builtin_bit_cast(float, u & 0xffff0000u); }
__device__ inline float bf2f(unsigned short s) { return __builtin_bit_cast(float, (unsigned)s << 16); }

// ---------------------------------------------------------------------------
__global__ void detect_flags(const int* __restrict__ ei, const int* __restrict__ gi,
                             int* __restrict__ flags, int n_nodes) {
  if (blockIdx.x == 0 && threadIdx.x == 0) {
    int nz = 0;
    for (int i = 1; i < 64; i += 2) nz |= ei[i];
    flags[0] = (nz == 0) ? 1 : 0;                       // 1 => edge_index is int64
    flags[1] = (gi[n_nodes - 1] == 0) ? 1 : 0;          // 1 => graph_indicator is int64
  }
}

// ---------------------------------------------------------------------------
// Phase A: bin edges into 8 dst-range group streams. Edge held in registers
// between count and write passes; pack = (g<<29)|(s<<13)|(d-g*rng), valid for
// s < 65536 and rng <= 8192. 8 global atomics per block (196 blocks).
__global__ __launch_bounds__(BIN_TPB) void bin_edges(const void* __restrict__ ei_raw,
                                                     const int* __restrict__ flags,
                                                     const float* __restrict__ ew,
                                                     int* __restrict__ gcur,
                                                     int2* __restrict__ binned, int E, int N) {
  __shared__ int cnt[8], base_s[8], loc[8];
  int t = threadIdx.x;
  if (t < 8) { cnt[t] = 0; loc[t] = 0; }
  __syncthreads();
  int rng = (N + 7) >> 3;
  bool is64 = flags[0] != 0;
  const long long* p64 = (const long long*)ei_raw;
  const int* p32 = (const int*)ei_raw;
  unsigned pk[BIN_EPT];
  float wv[BIN_EPT];
  int base = blockIdx.x * BIN_EPB;
#pragma unroll
  for (int j = 0; j < BIN_EPT; j++) {
    int e = base + j * BIN_TPB + t;
    pk[j] = 0xFFFFFFFFu;                 // sentinel (unreachable for valid s<50000)
    if (e < E) {
      int s = is64 ? (int)p64[e] : p32[e];
      int d = is64 ? (int)p64[E + e] : p32[E + e];
      int g = d / rng;
      pk[j] = ((unsigned)g << 29) | ((unsigned)s << 13) | (unsigned)(d - g * rng);
      wv[j] = ew[e];
      atomicAdd(&cnt[g], 1);
    }
  }
  __syncthreads();
  if (t < 8) base_s[t] = atomicAdd(&gcur[t], cnt[t]);
  __syncthreads();
#pragma unroll
  for (int j = 0; j < BIN_EPT; j++) {
    if (pk[j] != 0xFFFFFFFFu) {
      int g = pk[j] >> 29;
      int pos = atomicAdd(&loc[g], 1);
      binned[(size_t)g * E + base_s[g] + pos] =
          make_int2((int)pk[j], __builtin_bit_cast(int, wv[j]));
    }
  }
}

// ---------------------------------------------------------------------------
// Phase B: per-group sequential stream -> ELL scatter. Group g's ELL slice
// (2.4MB) + cursors stay L2-resident; blockIdx&7 keeps groups XCD-affine.
__global__ void scatter_ell2(const int2* __restrict__ binned, const int* __restrict__ gcnt,
                             int* __restrict__ cursor, int2* __restrict__ ell, int E, int N) {
  int group = blockIdx.x & 7;
  int chunk = blockIdx.x >> 3;
  int cnt = gcnt[group];
  int base = chunk * SC_CHUNK;
  if (base >= cnt) return;
  int rng = (N + 7) >> 3;
  int lo = group * rng;
  const int2* src = binned + (size_t)group * E;
  for (int i = 0; i < SC_CHUNK; i += 256) {
    int idx = base + i + threadIdx.x;
    if (idx < cnt) {
      int2 rec = src[idx];
      int d = lo + (rec.x & 8191);
      int s = (rec.x >> 13) & 0xFFFF;
      int pos = atomicAdd(&cursor[d], 1);
      if (pos < ELL_D)
        ell[(size_t)d * ELL_D + pos] = make_int2(s, rec.y);
    }
  }
}

// ---------------------------------------------------------------------------
__global__ void convert_w(const float* __restrict__ W1, const float* __restrict__ W2,
                          const float* __restrict__ W3, short* __restrict__ T1,
                          short* __restrict__ T2, short* __restrict__ T3) {
  int i = blockIdx.x * blockDim.x + threadIdx.x;   // 0 .. 3*16384-1
  int which = i >> 14, idx = i & 16383;
  int k = idx >> 7, n = idx & 127;
  const float* W = (which == 0) ? W1 : ((which == 1) ? W2 : W3);
  short* T = (which == 0) ? T1 : ((which == 1) ? T2 : T3);
  T[n * WT_STRIDE + k] = f2bf(W[idx]);
}

// ---------------------------------------------------------------------------
// C[n x 128](bf16) = A[n x 128] @ W[128 x 128] via bf16 MFMA (fp32 accumulate).
// 128-row block tile: each wave does 2x16 rows; each LDS B-fragment read
// feeds two MFMAs.
__global__ __launch_bounds__(256) void gemm_mfma(const float* __restrict__ Af,
                                                 const unsigned short* __restrict__ Abf,
                                                 const short* __restrict__ Wt,
                                                 unsigned short* __restrict__ C,
                                                 int n, int a_is_bf16) {
  __shared__ short Wlds[128 * WT_STRIDE];
  int t = threadIdx.x;
  {
    const ulonglong2* gsrc = (const ulonglong2*)Wt;
    ulonglong2* ldst = (ulonglong2*)Wlds;
    for (int i = t; i < (128 * WT_STRIDE) / 8; i += 256) ldst[i] = gsrc[i];
  }
  __syncthreads();

  int wave = t >> 6, lane = t & 63;
  int quad = lane >> 4, l15 = lane & 15;
  int m0 = blockIdx.x * 128 + wave * 32;

  short8 afrag[2][4];
#pragma unroll
  for (int rs = 0; rs < 2; rs++) {
    int m = m0 + rs * 16 + l15; if (m >= n) m = n - 1;
    if (a_is_bf16) {
      const unsigned short* Arow = Abf + (size_t)m * 128;
#pragma unroll
      for (int c = 0; c < 4; c++) afrag[rs][c] = *(const short8*)(Arow + c * 32 + quad * 8);
    } else {
      const float* Arow = Af + (size_t)m * 128;
#pragma unroll
      for (int c = 0; c < 4; c++) {
        int k0 = c * 32 + quad * 8;
        float4 x = *(const float4*)(Arow + k0);
        float4 y = *(const float4*)(Arow + k0 + 4);
        short8 a;
        a[0] = f2bf(x.x); a[1] = f2bf(x.y); a[2] = f2bf(x.z); a[3] = f2bf(x.w);
        a[4] = f2bf(y.x); a[5] = f2bf(y.y); a[6] = f2bf(y.z); a[7] = f2bf(y.w);
        afrag[rs][c] = a;
      }
    }
  }

  float4v acc[2][8];
#pragma unroll
  for (int rs = 0; rs < 2; rs++)
#pragma unroll
    for (int tt = 0; tt < 8; tt++) acc[rs][tt] = (float4v){0.f, 0.f, 0.f, 0.f};

#pragma unroll
  for (int c = 0; c < 4; c++) {
    int kb = c * 32 + quad * 8;
#pragma unroll
    for (int tt = 0; tt < 8; tt++) {
      short8 b = *(const short8*)&Wlds[(tt * 16 + l15) * WT_STRIDE + kb];
      acc[0][tt] = __builtin_amdgcn_mfma_f32_16x16x32_bf16(afrag[0][c], b, acc[0][tt], 0, 0, 0);
      acc[1][tt] = __builtin_amdgcn_mfma_f32_16x16x32_bf16(afrag[1][c], b, acc[1][tt], 0, 0, 0);
    }
  }

#pragma unroll
  for (int rs = 0; rs < 2; rs++) {
    int rbase = m0 + rs * 16 + quad * 4;
#pragma unroll
    for (int tt = 0; tt < 8; tt++) {
      int col = tt * 16 + l15;
#pragma unroll
      for (int r = 0; r < 4; r++) {
        int row = rbase + r;
        if (row < n) C[(size_t)row * 128 + col] = (unsigned short)f2bf(acc[rs][tt][r]);
      }
    }
  }
}

// ---------------------------------------------------------------------------
// g[node][:] = relu(bias + sum_e w_e * support[src_e][:]) — bf16 in/out.
// DETERMINISTIC: int32 fixed-point accumulators (scale 2^14) make the sum
// independent of ELL slot order (integer add is commutative). 16 lanes/node.
__global__ void aggregate(const unsigned short* __restrict__ support,
                          const int* __restrict__ deg_arr,
                          const int2* __restrict__ ell,
                          const float* __restrict__ bias, unsigned short* __restrict__ out,
                          const unsigned short* __restrict__ g1p,
                          const unsigned short* __restrict__ g2p,
                          const float* __restrict__ wa,
                          float* __restrict__ s_pre,
                          int n, int do_score) {
  int gid = blockIdx.x * blockDim.x + threadIdx.x;
  int node = gid >> 4, q = gid & 15;
  if (node >= n) return;
  int deg = deg_arr[node]; if (deg > ELL_D) deg = ELL_D;
  const int2* row = ell + (size_t)node * ELL_D;
  int acc[8];
#pragma unroll
  for (int j = 0; j < 8; j++) acc[j] = 0;
  const uint4* s4 = (const uint4*)support;

  int i = 0;
  for (; i + 3 < deg; i += 4) {
    int2 r0 = row[i], r1 = row[i + 1], r2 = row[i + 2], r3 = row[i + 3];
    float w0 = __builtin_bit_cast(float, r0.y) * FXS;
    float w1 = __builtin_bit_cast(float, r1.y) * FXS;
    float w2 = __builtin_bit_cast(float, r2.y) * FXS;
    float w3 = __builtin_bit_cast(float, r3.y) * FXS;
    uint4 v0 = s4[(size_t)r0.x * 16 + q];
    uint4 v1 = s4[(size_t)r1.x * 16 + q];
    uint4 v2 = s4[(size_t)r2.x * 16 + q];
    uint4 v3 = s4[(size_t)r3.x * 16 + q];
    acc[0] += __float2int_rn(w0 * bflo(v0.x)); acc[1] += __float2int_rn(w0 * bfhi(v0.x));
    acc[2] += __float2int_rn(w0 * bflo(v0.y)); acc[3] += __float2int_rn(w0 * bfhi(v0.y));
    acc[4] += __float2int_rn(w0 * bflo(v0.z)); acc[5] += __float2int_rn(w0 * bfhi(v0.z));
    acc[6] += __float2int_rn(w0 * bflo(v0.w)); acc[7] += __float2int_rn(w0 * bfhi(v0.w));
    acc[0] += __float2int_rn(w1 * bflo(v1.x)); acc[1] += __float2int_rn(w1 * bfhi(v1.x));
    acc[2] += __float2int_rn(w1 * bflo(v1.y)); acc[3] += __float2int_rn(w1 * bfhi(v1.y));
    acc[4] += __float2int_rn(w1 * bflo(v1.z)); acc[5] += __float2int_rn(w1 * bfhi(v1.z));
    acc[6] += __float2int_rn(w1 * bflo(v1.w)); acc[7] += __float2int_rn(w1 * bfhi(v1.w));
    acc[0] += __float2int_rn(w2 * bflo(v2.x)); acc[1] += __float2int_rn(w2 * bfhi(v2.x));
    acc[2] += __float2int_rn(w2 * bflo(v2.y)); acc[3] += __float2int_rn(w2 * bfhi(v2.y));
    acc[4] += __float2int_rn(w2 * bflo(v2.z)); acc[5] += __float2int_rn(w2 * bfhi(v2.z));
    acc[6] += __float2int_rn(w2 * bflo(v2.w)); acc[7] += __float2int_rn(w2 * bfhi(v2.w));
    acc[0] += __float2int_rn(w3 * bflo(v3.x)); acc[1] += __float2int_rn(w3 * bfhi(v3.x));
    acc[2] += __float2int_rn(w3 * bflo(v3.y)); acc[3] += __float2int_rn(w3 * bfhi(v3.y));
    acc[4] += __float2int_rn(w3 * bflo(v3.z)); acc[5] += __float2int_rn(w3 * bfhi(v3.z));
    acc[6] += __float2int_rn(w3 * bflo(v3.w)); acc[7] += __float2int_rn(w3 * bfhi(v3.w));
  }
  for (; i < deg; i++) {
    int2 r0 = row[i];
    float w0 = __builtin_bit_cast(float, r0.y) * FXS;
    uint4 v0 = s4[(size_t)r0.x * 16 + q];
    acc[0] += __float2int_rn(w0 * bflo(v0.x)); acc[1] += __float2int_rn(w0 * bfhi(v0.x));
    acc[2] += __float2int_rn(w0 * bflo(v0.y)); acc[3] += __float2int_rn(w0 * bfhi(v0.y));
    acc[4] += __float2int_rn(w0 * bflo(v0.z)); acc[5] += __float2int_rn(w0 * bfhi(v0.z));
    acc[6] += __float2int_rn(w0 * bflo(v0.w)); acc[7] += __float2int_rn(w0 * bfhi(v0.w));
  }

  float f[8];
#pragma unroll
  for (int j = 0; j < 8; j++) f[j] = (float)acc[j] * FXI;

  float4 b0 = ((const float4*)bias)[q * 2];
  float4 b1 = ((const float4*)bias)[q * 2 + 1];
  f[0] = fmaxf(f[0] + b0.x, 0.f); f[1] = fmaxf(f[1] + b0.y, 0.f);
  f[2] = fmaxf(f[2] + b0.z, 0.f); f[3] = fmaxf(f[3] + b0.w, 0.f);
  f[4] = fmaxf(f[4] + b1.x, 0.f); f[5] = fmaxf(f[5] + b1.y, 0.f);
  f[6] = fmaxf(f[6] + b1.z, 0.f); f[7] = fmaxf(f[7] + b1.w, 0.f);

  uint4 o;
  o.x = pack2bf(f[0], f[1]); o.y = pack2bf(f[2], f[3]);
  o.z = pack2bf(f[4], f[5]); o.w = pack2bf(f[6], f[7]);
  ((uint4*)out)[(size_t)node * 16 + q] = o;

  if (do_score) {
    int d0 = q * 8;
    uint4 u1 = ((const uint4*)g1p)[(size_t)node * 16 + q];
    uint4 u2 = ((const uint4*)g2p)[(size_t)node * 16 + q];
    const float* wa1 = wa + d0;
    const float* wa2 = wa + 128 + d0;
    const float* wa3 = wa + 256 + d0;
    float sc = bflo(u1.x) * wa1[0] + bfhi(u1.x) * wa1[1]
             + bflo(u1.y) * wa1[2] + bfhi(u1.y) * wa1[3]
             + bflo(u1.z) * wa1[4] + bfhi(u1.z) * wa1[5]
             + bflo(u1.w) * wa1[6] + bfhi(u1.w) * wa1[7]
             + bflo(u2.x) * wa2[0] + bfhi(u2.x) * wa2[1]
             + bflo(u2.y) * wa2[2] + bfhi(u2.y) * wa2[3]
             + bflo(u2.z) * wa2[4] + bfhi(u2.z) * wa2[5]
             + bflo(u2.w) * wa2[6] + bfhi(u2.w) * wa2[7];
#pragma unroll
    for (int j = 0; j < 8; j++) sc += f[j] * wa3[j];
#pragma unroll
    for (int m = 1; m < 16; m <<= 1) sc += __shfl_xor(sc, m, 64);
    if (q == 0) s_pre[node] = sc;
  }
}

// ---------------------------------------------------------------------------
// score = tanh(ba + sum_e w_e*s_pre[src]) — int32 fixed-point (deterministic).
__global__ void att_aggregate(const float* __restrict__ s_pre, const int* __restrict__ deg_arr,
                              const int2* __restrict__ ell,
                              const float* __restrict__ ba, float* __restrict__ score, int n) {
  int node = blockIdx.x * blockDim.x + threadIdx.x;
  if (node >= n) return;
  int deg = deg_arr[node]; if (deg > ELL_D) deg = ELL_D;
  const int2* row = ell + (size_t)node * ELL_D;
  int acc = 0;
  for (int i = 0; i < deg; i++) {
    int2 r = row[i];
    acc += __float2int_rn(__builtin_bit_cast(float, r.y) * FXS * s_pre[r.x]);
  }
  score[node] = tanhf((float)acc * FXI + ba[0]);
}

// ---------------------------------------------------------------------------
__global__ void graph_bounds(const void* __restrict__ gi_raw, const int* __restrict__ flags,
                             int* __restrict__ gstart, int n, int ngraphs) {
  int g = threadIdx.x;
  if (g > ngraphs) return;
  if (g == ngraphs) { gstart[g] = n; return; }
  bool is64 = flags[1] != 0;
  const long long* g64 = (const long long*)gi_raw;
  const int* g32 = (const int*)gi_raw;
  int lo = 0, hi = n;
  while (lo < hi) {
    int mid = (lo + hi) >> 1;
    long long v = is64 ? g64[mid] : (long long)g32[mid];
    if (v < (long long)g) lo = mid + 1; else hi = mid;
  }
  gstart[g] = lo;
}

// ---------------------------------------------------------------------------
__global__ __launch_bounds__(384) void pool_partial(const unsigned short* __restrict__ g1,
                                                    const unsigned short* __restrict__ g2,
                                                    const unsigned short* __restrict__ g3,
                                                    const float* __restrict__ score,
                                                    const int* __restrict__ gstart,
                                                    float* __restrict__ part) {
  int g = blockIdx.x / POOL_SEG, seg = blockIdx.x % POOL_SEG;
  int d = threadIdx.x;
  int sg = d >> 7, dd = d & 127;
  const unsigned short* gp = (sg == 0) ? g1 : ((sg == 1) ? g2 : g3);
  int s = gstart[g], e = gstart[g + 1];
  int len = e - s;
  int chunk = (len + POOL_SEG - 1) / POOL_SEG;
  int ns = s + seg * chunk;
  int ne = ns + chunk; if (ne > e) ne = e;
  float sum = 0.f, mx = -3.402823466e38f;
  for (int node = ns; node < ne; node++) {
    float sc = score[node];
    float v = bf2f(gp[(size_t)node * 128 + dd]) * sc;
    sum += v;
    mx = fmaxf(mx, v);
  }
  size_t base = (size_t)blockIdx.x * 768;
  part[base + d] = sum;
  part[base + 384 + d] = mx;
}

__global__ __launch_bounds__(384) void pool_combine(const float* __restrict__ part,
                                                    const int* __restrict__ gstart,
                                                    float* __restrict__ pooled) {
  int g = blockIdx.x;
  int d = threadIdx.x;
  float sum = 0.f, mx = -3.402823466e38f;
  for (int seg = 0; seg < POOL_SEG; seg++) {
    size_t base = ((size_t)g * POOL_SEG + seg) * 768;
    sum += part[base + d];
    mx = fmaxf(mx, part[base + 384 + d]);
  }
  float cnt = (float)(gstart[g + 1] - gstart[g]);
  pooled[(size_t)g * 768 + d] = sum / fmaxf(cnt, 1.0f);
  pooled[(size_t)g * 768 + 384 + d] = mx;
}

// ---------------------------------------------------------------------------
__global__ __launch_bounds__(128) void fg_partial(const float* __restrict__ pooled,
                                                  const float* __restrict__ Wf,
                                                  float* __restrict__ fgp) {
  int g = blockIdx.x / FG_KC, kc = blockIdx.x % FG_KC;
  int c = threadIdx.x;
  __shared__ float row[64];
  if (c < 64) row[c] = pooled[(size_t)g * 768 + kc * 64 + c];
  __syncthreads();
  const float* Wp = Wf + (size_t)kc * 64 * 128 + c;
  float acc = 0.f;
#pragma unroll 8
  for (int k = 0; k < 64; k++) acc += row[k] * Wp[k * 128];
  fgp[((size_t)g * FG_KC + kc) * 128 + c] = acc;
}

__global__ __launch_bounds__(128) void fg_combine(const float* __restrict__ fgp,
                                                  const float* __restrict__ bf,
                                                  float* __restrict__ out) {
  int g = blockIdx.x;
  int c = threadIdx.x;
  float acc = bf[c];
#pragma unroll
  for (int kc = 0; kc < FG_KC; kc++)
    acc += fgp[((size_t)g * FG_KC + kc) * 128 + c];
  out[(size_t)g * 128 + c] = fmaxf(acc, 0.f);
}

// ---------------------------------------------------------------------------
extern "C" void kernel_launch(void* const* d_in, const int* in_sizes, int n_in,
                              void* d_out, int out_size, void* d_ws, size_t ws_size,
                              hipStream_t stream) {
  const void* ei_raw = d_in[0];
  const float* ew    = (const float*)d_in[1];
  const float* X     = (const float*)d_in[2];
  const void* gi_raw = d_in[3];
  const float* W1 = (const float*)d_in[4];  const float* b1 = (const float*)d_in[5];
  const float* W2 = (const float*)d_in[6];  const float* b2 = (const float*)d_in[7];
  const float* W3 = (const float*)d_in[8];  const float* b3 = (const float*)d_in[9];
  const float* wa = (const float*)d_in[10]; const float* ba = (const float*)d_in[11];
  const float* Wf = (const float*)d_in[12]; const float* bf = (const float*)d_in[13];
  float* out = (float*)d_out;

  const int E = in_sizes[1];            // 800000
  const int N = in_sizes[2] / 128;      // 50000
  const int G = out_size / 128;         // 64

  char* ws = (char*)d_ws;
  size_t off = 0;
  auto take = [&](size_t bytes) {
    char* p = ws + off;
    off = (off + bytes + 255) & ~(size_t)255;
    return p;
  };
  int*   flags   = (int*)take(16);
  int*   cursor  = (int*)take((size_t)(N + 8) * 4);   // [N] node cursors + [8] group cursors
  int*   gcur    = cursor + N;
  int2*  binned  = (int2*)take((size_t)8 * E * 8);
  int2*  ell     = (int2*)take((size_t)N * ELL_D * 8);
  short* wt1     = (short*)take((size_t)128 * WT_STRIDE * 2);
  short* wt2     = (short*)take((size_t)128 * WT_STRIDE * 2);
  short* wt3     = (short*)take((size_t)128 * WT_STRIDE * 2);
  unsigned short* support = (unsigned short*)take((size_t)N * 128 * 2);
  unsigned short* g1      = (unsigned short*)take((size_t)N * 128 * 2);
  unsigned short* g2      = (unsigned short*)take((size_t)N * 128 * 2);
  unsigned short* g3      = (unsigned short*)take((size_t)N * 128 * 2);
  float* s_pre   = (float*)take((size_t)N * 4);
  float* score   = (float*)take((size_t)N * 4);
  int*   gstart  = (int*)take((size_t)(G + 1) * 4);
  float* part    = (float*)take((size_t)G * POOL_SEG * 768 * 4);
  float* pooled  = (float*)take((size_t)G * 768 * 4);
  float* fgp     = (float*)take((size_t)G * FG_KC * 128 * 4);
  if (off > ws_size) return;

  hipMemsetAsync(cursor, 0, (size_t)(N + 8) * 4, stream);
  detect_flags<<<1, 64, 0, stream>>>((const int*)ei_raw, (const int*)gi_raw, flags, N);
  convert_w<<<(3 * 16384 + 255) / 256, 256, 0, stream>>>(W1, W2, W3, wt1, wt2, wt3);
  bin_edges<<<(E + BIN_EPB - 1) / BIN_EPB, BIN_TPB, 0, stream>>>(ei_raw, flags, ew,
                                                                 gcur, binned, E, N);
  {
    int chunks = (E + SC_CHUNK - 1) / SC_CHUNK;
    scatter_ell2<<<8 * chunks, 256, 0, stream>>>(binned, gcur, cursor, ell, E, N);
  }

  const int GB = (N + 127) / 128;
  const int AB = (N * 16 + 255) / 256;
  // layer 1
  gemm_mfma<<<GB, 256, 0, stream>>>(X, (const unsigned short*)nullptr, wt1, support, N, 0);
  aggregate<<<AB, 256, 0, stream>>>(support, cursor, ell, b1, g1,
                                    nullptr, nullptr, nullptr, nullptr, N, 0);
  // layer 2
  gemm_mfma<<<GB, 256, 0, stream>>>((const float*)nullptr, g1, wt2, support, N, 1);
  aggregate<<<AB, 256, 0, stream>>>(support, cursor, ell, b2, g2,
                                    nullptr, nullptr, nullptr, nullptr, N, 0);
  // layer 3 (+ fused attention-score partial)
  gemm_mfma<<<GB, 256, 0, stream>>>((const float*)nullptr, g2, wt3, support, N, 1);
  aggregate<<<AB, 256, 0, stream>>>(support, cursor, ell, b3, g3,
                                    g1, g2, wa, s_pre, N, 1);

  // attention edge-aggregate + tanh
  att_aggregate<<<(N + 255) / 256, 256, 0, stream>>>(s_pre, cursor, ell, ba, score, N);

  // pooling + readout
  graph_bounds<<<1, 128, 0, stream>>>(gi_raw, flags, gstart, N, G);
  pool_partial<<<G * POOL_SEG, 384, 0, stream>>>(g1, g2, g3, score, gstart, part);
  pool_combine<<<G, 384, 0, stream>>>(part, gstart, pooled);
  fg_partial<<<G * FG_KC, 128, 0, stream>>>(pooled, Wf, fgp);
  fg_combine<<<G, 128, 0, stream>>>(fgp, bf, out);
}

// Round 12
// 323.451 us; speedup vs baseline: 1.0302x; 1.0302x over previous
//
#include <hip/hip_runtime.h>
#include <math.h>

#define HID 128
#define POOL_SEG 16
#define WT_STRIDE 136     // padded k-stride (shorts) for transposed bf16 W
#define ELL_D 48          // ELL slots/node (deg~Binom mean16 sd4; P(>48)~1e-15)
#define SC_CHUNK 2048     // edges per scatter block-chunk
#define FXS 16384.0f      // fixed-point scale (2^14) for deterministic edge sums
#define FXI (1.0f/16384.0f)
#define FG_KC 12          // final-gemm k-chunks (768 = 12 * 64)

typedef __attribute__((ext_vector_type(8))) short short8;   // 8 bf16 = 4 VGPRs
typedef __attribute__((ext_vector_type(4))) float float4v;  // 4 fp32 acc

__device__ inline short f2bf(float f) {
  unsigned u = __builtin_bit_cast(unsigned, f);
  unsigned r = (u + 0x7fff + ((u >> 16) & 1)) >> 16;   // RNE
  return (short)r;
}
__device__ inline unsigned pack2bf(float lo, float hi) {
  return (unsigned)(unsigned short)f2bf(lo) | ((unsigned)(unsigned short)f2bf(hi) << 16);
}
__device__ inline float bflo(unsigned u) { return __builtin_bit_cast(float, u << 16); }
__device__ inline float bfhi(unsigned u) { return __builtin_bit_cast(float, u & 0xffff0000u); }
__device__ inline float bf2f(unsigned short s) { return __builtin_bit_cast(float, (unsigned)s << 16); }
__device__ inline unsigned short f2h(float f) {
  _Float16 h = (_Float16)f;                       // v_cvt_f16_f32, RNE
  return __builtin_bit_cast(unsigned short, h);
}
__device__ inline float h2f(unsigned short hb) {
  return (float)__builtin_bit_cast(_Float16, hb); // v_cvt_f32_f16
}

// ---------------------------------------------------------------------------
__global__ void detect_flags(const int* __restrict__ ei, const int* __restrict__ gi,
                             int* __restrict__ flags, int n_nodes) {
  if (blockIdx.x == 0 && threadIdx.x == 0) {
    int nz = 0;
    for (int i = 1; i < 64; i += 2) nz |= ei[i];
    flags[0] = (nz == 0) ? 1 : 0;                       // 1 => edge_index is int64
    flags[1] = (gi[n_nodes - 1] == 0) ? 1 : 0;          // 1 => graph_indicator is int64
  }
}

// ---------------------------------------------------------------------------
// One linear pass: edge_index + ew -> packed 8B stream {(d<<16)|s, fp32 w}.
// (d, s < 65536 on this problem; 6.4MB total — per-XCD L2-absorbable.)
__global__ void prep_edges(const void* __restrict__ ei_raw, const int* __restrict__ flags,
                           const float* __restrict__ ew, int2* __restrict__ packed, int E) {
  int e = blockIdx.x * blockDim.x + threadIdx.x;
  if (e >= E) return;
  int s, d;
  if (flags[0]) {
    const long long* p = (const long long*)ei_raw;
    s = (int)p[e]; d = (int)p[E + e];
  } else {
    const int* p = (const int*)ei_raw;
    s = p[e]; d = p[E + e];
  }
  packed[e] = make_int2((d << 16) | s, __builtin_bit_cast(int, ew[e]));
}

// ---------------------------------------------------------------------------
// XCD-partitioned ELL scatter: block b handles dst range (b&7), chunk (b>>3).
// 4B ELL records {(s<<16)|fp16(w)}; per-group ELL slice 1.2MB -> L2-resident.
// Slot order nondeterministic; downstream fixed-point sums make it benign.
__global__ void scatter_ell(const int2* __restrict__ packed, int* __restrict__ cursor,
                            unsigned* __restrict__ ell, int E, int N) {
  int group = blockIdx.x & 7;
  int chunk = blockIdx.x >> 3;
  int rng = (N + 7) >> 3;
  int lo = group * rng;
  int hi = lo + rng; if (hi > N) hi = N;
  int base = chunk * SC_CHUNK;
  for (int i = 0; i < SC_CHUNK; i += 256) {
    int e = base + i + threadIdx.x;
    if (e < E) {
      int2 rec = packed[e];
      int d = ((unsigned)rec.x) >> 16;
      if (d >= lo && d < hi) {
        unsigned s = (unsigned)rec.x & 0xFFFFu;
        unsigned short wh = f2h(__builtin_bit_cast(float, rec.y));
        int pos = atomicAdd(&cursor[d], 1);
        if (pos < ELL_D)
          ell[(size_t)d * ELL_D + pos] = (s << 16) | (unsigned)wh;
      }
    }
  }
}

// ---------------------------------------------------------------------------
__global__ void convert_w(const float* __restrict__ W1, const float* __restrict__ W2,
                          const float* __restrict__ W3, short* __restrict__ T1,
                          short* __restrict__ T2, short* __restrict__ T3) {
  int i = blockIdx.x * blockDim.x + threadIdx.x;   // 0 .. 3*16384-1
  int which = i >> 14, idx = i & 16383;
  int k = idx >> 7, n = idx & 127;
  const float* W = (which == 0) ? W1 : ((which == 1) ? W2 : W3);
  short* T = (which == 0) ? T1 : ((which == 1) ? T2 : T3);
  T[n * WT_STRIDE + k] = f2bf(W[idx]);
}

// ---------------------------------------------------------------------------
// C[n x 128](bf16) = A[n x 128] @ W[128 x 128] via bf16 MFMA (fp32 accumulate).
// 64-row block tile (R10-proven config).
__global__ __launch_bounds__(256) void gemm_mfma(const float* __restrict__ Af,
                                                 const unsigned short* __restrict__ Abf,
                                                 const short* __restrict__ Wt,
                                                 unsigned short* __restrict__ C,
                                                 int n, int a_is_bf16) {
  __shared__ short Wlds[128 * WT_STRIDE];
  int t = threadIdx.x;
  {
    const ulonglong2* gsrc = (const ulonglong2*)Wt;
    ulonglong2* ldst = (ulonglong2*)Wlds;
    for (int i = t; i < (128 * WT_STRIDE) / 8; i += 256) ldst[i] = gsrc[i];
  }
  __syncthreads();

  int wave = t >> 6, lane = t & 63;
  int quad = lane >> 4, l15 = lane & 15;
  int m0 = blockIdx.x * 64 + wave * 16;

  int m = m0 + l15; if (m >= n) m = n - 1;
  short8 afrag[4];
  if (a_is_bf16) {
    const unsigned short* Arow = Abf + (size_t)m * 128;
#pragma unroll
    for (int c = 0; c < 4; c++) afrag[c] = *(const short8*)(Arow + c * 32 + quad * 8);
  } else {
    const float* Arow = Af + (size_t)m * 128;
#pragma unroll
    for (int c = 0; c < 4; c++) {
      int k0 = c * 32 + quad * 8;
      float4 x = *(const float4*)(Arow + k0);
      float4 y = *(const float4*)(Arow + k0 + 4);
      short8 a;
      a[0] = f2bf(x.x); a[1] = f2bf(x.y); a[2] = f2bf(x.z); a[3] = f2bf(x.w);
      a[4] = f2bf(y.x); a[5] = f2bf(y.y); a[6] = f2bf(y.z); a[7] = f2bf(y.w);
      afrag[c] = a;
    }
  }

  float4v acc[8];
#pragma unroll
  for (int tt = 0; tt < 8; tt++) acc[tt] = (float4v){0.f, 0.f, 0.f, 0.f};

#pragma unroll
  for (int c = 0; c < 4; c++) {
    int kb = c * 32 + quad * 8;
#pragma unroll
    for (int tt = 0; tt < 8; tt++) {
      const short8* bp = (const short8*)&Wlds[(tt * 16 + l15) * WT_STRIDE + kb];
      acc[tt] = __builtin_amdgcn_mfma_f32_16x16x32_bf16(afrag[c], *bp, acc[tt], 0, 0, 0);
    }
  }

  int rbase = m0 + quad * 4;
#pragma unroll
  for (int tt = 0; tt < 8; tt++) {
    int col = tt * 16 + l15;
#pragma unroll
    for (int r = 0; r < 4; r++) {
      int row = rbase + r;
      if (row < n) C[(size_t)row * 128 + col] = (unsigned short)f2bf(acc[tt][r]);
    }
  }
}

// ---------------------------------------------------------------------------
// g[node][:] = relu(bias + sum_e w_e * support[src_e][:]) — bf16 in/out.
// DETERMINISTIC: int32 fixed-point accumulators (scale 2^14), slot-order
// independent. 16 lanes/node; 4B ELL records {(s<<16)|fp16(w)}.
__global__ void aggregate(const unsigned short* __restrict__ support,
                          const int* __restrict__ deg_arr,
                          const unsigned* __restrict__ ell,
                          const float* __restrict__ bias, unsigned short* __restrict__ out,
                          const unsigned short* __restrict__ g1p,
                          const unsigned short* __restrict__ g2p,
                          const float* __restrict__ wa,
                          float* __restrict__ s_pre,
                          int n, int do_score) {
  int gid = blockIdx.x * blockDim.x + threadIdx.x;
  int node = gid >> 4, q = gid & 15;
  if (node >= n) return;
  int deg = deg_arr[node]; if (deg > ELL_D) deg = ELL_D;
  const unsigned* row = ell + (size_t)node * ELL_D;
  int acc[8];
#pragma unroll
  for (int j = 0; j < 8; j++) acc[j] = 0;
  const uint4* s4 = (const uint4*)support;

  int i = 0;
  for (; i + 3 < deg; i += 4) {
    unsigned r0 = row[i], r1 = row[i + 1], r2 = row[i + 2], r3 = row[i + 3];
    float w0 = h2f((unsigned short)(r0 & 0xFFFF)) * FXS;
    float w1 = h2f((unsigned short)(r1 & 0xFFFF)) * FXS;
    float w2 = h2f((unsigned short)(r2 & 0xFFFF)) * FXS;
    float w3 = h2f((unsigned short)(r3 & 0xFFFF)) * FXS;
    uint4 v0 = s4[(size_t)(r0 >> 16) * 16 + q];
    uint4 v1 = s4[(size_t)(r1 >> 16) * 16 + q];
    uint4 v2 = s4[(size_t)(r2 >> 16) * 16 + q];
    uint4 v3 = s4[(size_t)(r3 >> 16) * 16 + q];
    acc[0] += __float2int_rn(w0 * bflo(v0.x)); acc[1] += __float2int_rn(w0 * bfhi(v0.x));
    acc[2] += __float2int_rn(w0 * bflo(v0.y)); acc[3] += __float2int_rn(w0 * bfhi(v0.y));
    acc[4] += __float2int_rn(w0 * bflo(v0.z)); acc[5] += __float2int_rn(w0 * bfhi(v0.z));
    acc[6] += __float2int_rn(w0 * bflo(v0.w)); acc[7] += __float2int_rn(w0 * bfhi(v0.w));
    acc[0] += __float2int_rn(w1 * bflo(v1.x)); acc[1] += __float2int_rn(w1 * bfhi(v1.x));
    acc[2] += __float2int_rn(w1 * bflo(v1.y)); acc[3] += __float2int_rn(w1 * bfhi(v1.y));
    acc[4] += __float2int_rn(w1 * bflo(v1.z)); acc[5] += __float2int_rn(w1 * bfhi(v1.z));
    acc[6] += __float2int_rn(w1 * bflo(v1.w)); acc[7] += __float2int_rn(w1 * bfhi(v1.w));
    acc[0] += __float2int_rn(w2 * bflo(v2.x)); acc[1] += __float2int_rn(w2 * bfhi(v2.x));
    acc[2] += __float2int_rn(w2 * bflo(v2.y)); acc[3] += __float2int_rn(w2 * bfhi(v2.y));
    acc[4] += __float2int_rn(w2 * bflo(v2.z)); acc[5] += __float2int_rn(w2 * bfhi(v2.z));
    acc[6] += __float2int_rn(w2 * bflo(v2.w)); acc[7] += __float2int_rn(w2 * bfhi(v2.w));
    acc[0] += __float2int_rn(w3 * bflo(v3.x)); acc[1] += __float2int_rn(w3 * bfhi(v3.x));
    acc[2] += __float2int_rn(w3 * bflo(v3.y)); acc[3] += __float2int_rn(w3 * bfhi(v3.y));
    acc[4] += __float2int_rn(w3 * bflo(v3.z)); acc[5] += __float2int_rn(w3 * bfhi(v3.z));
    acc[6] += __float2int_rn(w3 * bflo(v3.w)); acc[7] += __float2int_rn(w3 * bfhi(v3.w));
  }
  for (; i < deg; i++) {
    unsigned r0 = row[i];
    float w0 = h2f((unsigned short)(r0 & 0xFFFF)) * FXS;
    uint4 v0 = s4[(size_t)(r0 >> 16) * 16 + q];
    acc[0] += __float2int_rn(w0 * bflo(v0.x)); acc[1] += __float2int_rn(w0 * bfhi(v0.x));
    acc[2] += __float2int_rn(w0 * bflo(v0.y)); acc[3] += __float2int_rn(w0 * bfhi(v0.y));
    acc[4] += __float2int_rn(w0 * bflo(v0.z)); acc[5] += __float2int_rn(w0 * bfhi(v0.z));
    acc[6] += __float2int_rn(w0 * bflo(v0.w)); acc[7] += __float2int_rn(w0 * bfhi(v0.w));
  }

  float f[8];
#pragma unroll
  for (int j = 0; j < 8; j++) f[j] = (float)acc[j] * FXI;

  float4 b0 = ((const float4*)bias)[q * 2];
  float4 b1 = ((const float4*)bias)[q * 2 + 1];
  f[0] = fmaxf(f[0] + b0.x, 0.f); f[1] = fmaxf(f[1] + b0.y, 0.f);
  f[2] = fmaxf(f[2] + b0.z, 0.f); f[3] = fmaxf(f[3] + b0.w, 0.f);
  f[4] = fmaxf(f[4] + b1.x, 0.f); f[5] = fmaxf(f[5] + b1.y, 0.f);
  f[6] = fmaxf(f[6] + b1.z, 0.f); f[7] = fmaxf(f[7] + b1.w, 0.f);

  uint4 o;
  o.x = pack2bf(f[0], f[1]); o.y = pack2bf(f[2], f[3]);
  o.z = pack2bf(f[4], f[5]); o.w = pack2bf(f[6], f[7]);
  ((uint4*)out)[(size_t)node * 16 + q] = o;

  if (do_score) {
    int d0 = q * 8;
    uint4 u1 = ((const uint4*)g1p)[(size_t)node * 16 + q];
    uint4 u2 = ((const uint4*)g2p)[(size_t)node * 16 + q];
    const float* wa1 = wa + d0;
    const float* wa2 = wa + 128 + d0;
    const float* wa3 = wa + 256 + d0;
    float sc = bflo(u1.x) * wa1[0] + bfhi(u1.x) * wa1[1]
             + bflo(u1.y) * wa1[2] + bfhi(u1.y) * wa1[3]
             + bflo(u1.z) * wa1[4] + bfhi(u1.z) * wa1[5]
             + bflo(u1.w) * wa1[6] + bfhi(u1.w) * wa1[7]
             + bflo(u2.x) * wa2[0] + bfhi(u2.x) * wa2[1]
             + bflo(u2.y) * wa2[2] + bfhi(u2.y) * wa2[3]
             + bflo(u2.z) * wa2[4] + bfhi(u2.z) * wa2[5]
             + bflo(u2.w) * wa2[6] + bfhi(u2.w) * wa2[7];
#pragma unroll
    for (int j = 0; j < 8; j++) sc += f[j] * wa3[j];
#pragma unroll
    for (int m = 1; m < 16; m <<= 1) sc += __shfl_xor(sc, m, 64);
    if (q == 0) s_pre[node] = sc;
  }
}

// ---------------------------------------------------------------------------
// score = tanh(ba + sum_e w_e*s_pre[src]) — int32 fixed-point (deterministic).
__global__ void att_aggregate(const float* __restrict__ s_pre, const int* __restrict__ deg_arr,
                              const unsigned* __restrict__ ell,
                              const float* __restrict__ ba, float* __restrict__ score, int n) {
  int node = blockIdx.x * blockDim.x + threadIdx.x;
  if (node >= n) return;
  int deg = deg_arr[node]; if (deg > ELL_D) deg = ELL_D;
  const unsigned* row = ell + (size_t)node * ELL_D;
  int acc = 0;
  for (int i = 0; i < deg; i++) {
    unsigned r = row[i];
    acc += __float2int_rn(h2f((unsigned short)(r & 0xFFFF)) * FXS * s_pre[r >> 16]);
  }
  score[node] = tanhf((float)acc * FXI + ba[0]);
}

// ---------------------------------------------------------------------------
__global__ void graph_bounds(const void* __restrict__ gi_raw, const int* __restrict__ flags,
                             int* __restrict__ gstart, int n, int ngraphs) {
  int g = threadIdx.x;
  if (g > ngraphs) return;
  if (g == ngraphs) { gstart[g] = n; return; }
  bool is64 = flags[1] != 0;
  const long long* g64 = (const long long*)gi_raw;
  const int* g32 = (const int*)gi_raw;
  int lo = 0, hi = n;
  while (lo < hi) {
    int mid = (lo + hi) >> 1;
    long long v = is64 ? g64[mid] : (long long)g32[mid];
    if (v < (long long)g) lo = mid + 1; else hi = mid;
  }
  gstart[g] = lo;
}

// ---------------------------------------------------------------------------
__global__ __launch_bounds__(384) void pool_partial(const unsigned short* __restrict__ g1,
                                                    const unsigned short* __restrict__ g2,
                                                    const unsigned short* __restrict__ g3,
                                                    const float* __restrict__ score,
                                                    const int* __restrict__ gstart,
                                                    float* __restrict__ part) {
  int g = blockIdx.x / POOL_SEG, seg = blockIdx.x % POOL_SEG;
  int d = threadIdx.x;
  int sg = d >> 7, dd = d & 127;
  const unsigned short* gp = (sg == 0) ? g1 : ((sg == 1) ? g2 : g3);
  int s = gstart[g], e = gstart[g + 1];
  int len = e - s;
  int chunk = (len + POOL_SEG - 1) / POOL_SEG;
  int ns = s + seg * chunk;
  int ne = ns + chunk; if (ne > e) ne = e;
  float sum = 0.f, mx = -3.402823466e38f;
  for (int node = ns; node < ne; node++) {
    float sc = score[node];
    float v = bf2f(gp[(size_t)node * 128 + dd]) * sc;
    sum += v;
    mx = fmaxf(mx, v);
  }
  size_t base = (size_t)blockIdx.x * 768;
  part[base + d] = sum;
  part[base + 384 + d] = mx;
}

__global__ __launch_bounds__(384) void pool_combine(const float* __restrict__ part,
                                                    const int* __restrict__ gstart,
                                                    float* __restrict__ pooled) {
  int g = blockIdx.x;
  int d = threadIdx.x;
  float sum = 0.f, mx = -3.402823466e38f;
  for (int seg = 0; seg < POOL_SEG; seg++) {
    size_t base = ((size_t)g * POOL_SEG + seg) * 768;
    sum += part[base + d];
    mx = fmaxf(mx, part[base + 384 + d]);
  }
  float cnt = (float)(gstart[g + 1] - gstart[g]);
  pooled[(size_t)g * 768 + d] = sum / fmaxf(cnt, 1.0f);
  pooled[(size_t)g * 768 + 384 + d] = mx;
}

// ---------------------------------------------------------------------------
__global__ __launch_bounds__(128) void fg_partial(const float* __restrict__ pooled,
                                                  const float* __restrict__ Wf,
                                                  float* __restrict__ fgp) {
  int g = blockIdx.x / FG_KC, kc = blockIdx.x % FG_KC;
  int c = threadIdx.x;
  __shared__ float row[64];
  if (c < 64) row[c] = pooled[(size_t)g * 768 + kc * 64 + c];
  __syncthreads();
  const float* Wp = Wf + (size_t)kc * 64 * 128 + c;
  float acc = 0.f;
#pragma unroll 8
  for (int k = 0; k < 64; k++) acc += row[k] * Wp[k * 128];
  fgp[((size_t)g * FG_KC + kc) * 128 + c] = acc;
}

__global__ __launch_bounds__(128) void fg_combine(const float* __restrict__ fgp,
                                                  const float* __restrict__ bf,
                                                  float* __restrict__ out) {
  int g = blockIdx.x;
  int c = threadIdx.x;
  float acc = bf[c];
#pragma unroll
  for (int kc = 0; kc < FG_KC; kc++)
    acc += fgp[((size_t)g * FG_KC + kc) * 128 + c];
  out[(size_t)g * 128 + c] = fmaxf(acc, 0.f);
}

// ---------------------------------------------------------------------------
extern "C" void kernel_launch(void* const* d_in, const int* in_sizes, int n_in,
                              void* d_out, int out_size, void* d_ws, size_t ws_size,
                              hipStream_t stream) {
  const void* ei_raw = d_in[0];
  const float* ew    = (const float*)d_in[1];
  const float* X     = (const float*)d_in[2];
  const void* gi_raw = d_in[3];
  const float* W1 = (const float*)d_in[4];  const float* b1 = (const float*)d_in[5];
  const float* W2 = (const float*)d_in[6];  const float* b2 = (const float*)d_in[7];
  const float* W3 = (const float*)d_in[8];  const float* b3 = (const float*)d_in[9];
  const float* wa = (const float*)d_in[10]; const float* ba = (const float*)d_in[11];
  const float* Wf = (const float*)d_in[12]; const float* bf = (const float*)d_in[13];
  float* out = (float*)d_out;

  const int E = in_sizes[1];            // 800000
  const int N = in_sizes[2] / 128;      // 50000
  const int G = out_size / 128;         // 64

  char* ws = (char*)d_ws;
  size_t off = 0;
  auto take = [&](size_t bytes) {
    char* p = ws + off;
    off = (off + bytes + 255) & ~(size_t)255;
    return p;
  };
  int*      flags   = (int*)take(16);
  int*      cursor  = (int*)take((size_t)N * 4);
  int2*     packed  = (int2*)take((size_t)E * 8);
  unsigned* ell     = (unsigned*)take((size_t)N * ELL_D * 4);
  short*    wt1     = (short*)take((size_t)128 * WT_STRIDE * 2);
  short*    wt2     = (short*)take((size_t)128 * WT_STRIDE * 2);
  short*    wt3     = (short*)take((size_t)128 * WT_STRIDE * 2);
  unsigned short* support = (unsigned short*)take((size_t)N * 128 * 2);
  unsigned short* g1      = (unsigned short*)take((size_t)N * 128 * 2);
  unsigned short* g2      = (unsigned short*)take((size_t)N * 128 * 2);
  unsigned short* g3      = (unsigned short*)take((size_t)N * 128 * 2);
  float* s_pre   = (float*)take((size_t)N * 4);
  float* score   = (float*)take((size_t)N * 4);
  int*   gstart  = (int*)take((size_t)(G + 1) * 4);
  float* part    = (float*)take((size_t)G * POOL_SEG * 768 * 4);
  float* pooled  = (float*)take((size_t)G * 768 * 4);
  float* fgp     = (float*)take((size_t)G * FG_KC * 128 * 4);
  if (off > ws_size) return;

  hipMemsetAsync(cursor, 0, (size_t)N * 4, stream);
  detect_flags<<<1, 64, 0, stream>>>((const int*)ei_raw, (const int*)gi_raw, flags, N);
  prep_edges<<<(E + 255) / 256, 256, 0, stream>>>(ei_raw, flags, ew, packed, E);
  convert_w<<<(3 * 16384 + 255) / 256, 256, 0, stream>>>(W1, W2, W3, wt1, wt2, wt3);
  {
    int chunks = (E + SC_CHUNK - 1) / SC_CHUNK;
    scatter_ell<<<8 * chunks, 256, 0, stream>>>(packed, cursor, ell, E, N);
  }

  const int GB = (N + 63) / 64;
  const int AB = (N * 16 + 255) / 256;
  // layer 1
  gemm_mfma<<<GB, 256, 0, stream>>>(X, (const unsigned short*)nullptr, wt1, support, N, 0);
  aggregate<<<AB, 256, 0, stream>>>(support, cursor, ell, b1, g1,
                                    nullptr, nullptr, nullptr, nullptr, N, 0);
  // layer 2
  gemm_mfma<<<GB, 256, 0, stream>>>((const float*)nullptr, g1, wt2, support, N, 1);
  aggregate<<<AB, 256, 0, stream>>>(support, cursor, ell, b2, g2,
                                    nullptr, nullptr, nullptr, nullptr, N, 0);
  // layer 3 (+ fused attention-score partial)
  gemm_mfma<<<GB, 256, 0, stream>>>((const float*)nullptr, g2, wt3, support, N, 1);
  aggregate<<<AB, 256, 0, stream>>>(support, cursor, ell, b3, g3,
                                    g1, g2, wa, s_pre, N, 1);

  // attention edge-aggregate + tanh
  att_aggregate<<<(N + 255) / 256, 256, 0, stream>>>(s_pre, cursor, ell, ba, score, N);

  // pooling + readout
  graph_bounds<<<1, 128, 0, stream>>>(gi_raw, flags, gstart, N, G);
  pool_partial<<<G * POOL_SEG, 384, 0, stream>>>(g1, g2, g3, score, gstart, part);
  pool_combine<<<G, 384, 0, stream>>>(part, gstart, pooled);
  fg_partial<<<G * FG_KC, 128, 0, stream>>>(pooled, Wf, fgp);
  fg_combine<<<G, 128, 0, stream>>>(fgp, bf, out);
}